// Round 1
// baseline (549.790 us; speedup 1.0000x reference)
//
#include <hip/hip_runtime.h>

// Problem constants (B,C,H,W) = (8,32,512,512), K=9
#define HH 512
#define WW 512
#define PLANES 256   // B*C
#define SEGS 8
#define SEGROWS 64   // HH / SEGS
#define CG 128       // float4 column-groups per row (WW/4)

__device__ __forceinline__ int imax(int a, int b) { return a > b ? a : b; }

// out = (1/8) * [ sum (81 + ch(h)*cw(w)) * x^2  -  2 * sum RowBox9(x) * ColBox9(x) ]
__global__ __launch_bounds__(256, 4) void scc_kernel(const float* __restrict__ img,
                                                     float* __restrict__ out) {
    const int tid   = blockIdx.x * 256 + threadIdx.x;
    const int g     = tid & (CG - 1);      // column group: cols [4g, 4g+3]
    const int rest  = tid >> 7;
    const int seg   = rest & (SEGS - 1);
    const int plane = rest >> 3;

    const float* base = img + (size_t)plane * (HH * WW);
    const int r0 = seg * SEGROWS;

    // per-column border weight cw(w) = #valid horizontal window positions
    float cw[4];
#pragma unroll
    for (int c = 0; c < 4; ++c) {
        int w = 4 * g + c;
        cw[c] = (float)(9 - imax(0, 4 - w) - imax(0, w - (WW - 5)));
    }

    float xr[9][4];   // ring of x rows (depth 9, static indices via unroll)
    float Rr[9][4];   // ring of row-box values
    float V[4] = {0.f, 0.f, 0.f, 0.f};
#pragma unroll
    for (int j = 0; j < 9; ++j)
#pragma unroll
        for (int c = 0; c < 4; ++c) { xr[j][c] = 0.f; Rr[j][c] = 0.f; }

    float acc = 0.f;
    int r = r0 - 4;  // streamed row; center is h = r - 4

    auto body = [&](int j, bool do_acc) {
        const bool rowv = (r >= 0) & (r < HH);
        const float4* rowp = (const float4*)(base + (ptrdiff_t)r * WW);
        const float4 z4 = make_float4(0.f, 0.f, 0.f, 0.f);
        float4 lc = (rowv && g > 0)      ? rowp[g - 1] : z4;
        float4 cc = rowv                 ? rowp[g]     : z4;
        float4 rc = (rowv && g < CG - 1) ? rowp[g + 1] : z4;
        float v0 = lc.x, v1 = lc.y, v2 = lc.z, v3 = lc.w;
        float v4 = cc.x, v5 = cc.y, v6 = cc.z, v7 = cc.w;
        float v8 = rc.x, v9 = rc.y, v10 = rc.z, v11 = rc.w;

        // horizontal 9-sums for the 4 owned columns (sliding)
        float R0 = ((v0 + v1) + (v2 + v3)) + ((v4 + v5) + (v6 + v7)) + v8;
        float R1 = R0 - v0 + v9;
        float R2 = R1 - v1 + v10;
        float R3 = R2 - v2 + v11;
        float Rn[4] = {R0, R1, R2, R3};
        float xn[4] = {v4, v5, v6, v7};

#pragma unroll
        for (int c = 0; c < 4; ++c) {
            V[c] += xn[c] - xr[j][c];   // xr[j] holds row r-9 (or 0 in warmup)
            xr[j][c] = xn[c];
            Rr[j][c] = Rn[c];
        }
        if (do_acc) {
            const int h = r - 4;
            const float chf = (float)(9 - imax(0, 4 - h) - imax(0, h - (HH - 5)));
            const int js = (j + 5) % 9;  // slot holding row h = r-4
#pragma unroll
            for (int c = 0; c < 4; ++c) {
                float xc  = xr[js][c];
                float wgt = fmaf(chf, cw[c], 81.f);
                acc = fmaf(wgt * xc, xc, acc);
                acc = fmaf(-2.f * Rr[js][c], V[c], acc);
            }
        }
        ++r;
    };

    // warmup: 9 rows fill the rings; first center (h = r0) completes at i == 8
#pragma unroll
    for (int j = 0; j < 9; ++j) body(j, j == 8);
    // main: 7 more groups of 9 rows, all produce centers (total 64 centers)
    for (int grp = 1; grp < 8; ++grp) {
#pragma unroll
        for (int j = 0; j < 9; ++j) body(j, true);
    }

    // reduce: wave64 shuffle -> LDS -> one atomic per block
#pragma unroll
    for (int off = 32; off > 0; off >>= 1)
        acc += __shfl_xor(acc, off, 64);
    __shared__ float wsum[4];
    const int lane = threadIdx.x & 63;
    const int wv   = threadIdx.x >> 6;
    if (lane == 0) wsum[wv] = acc;
    __syncthreads();
    if (threadIdx.x == 0) {
        float s = (wsum[0] + wsum[1]) + (wsum[2] + wsum[3]);
        atomicAdd(out, 0.125f * s);  // mean over batch (B = 8)
    }
}

extern "C" void kernel_launch(void* const* d_in, const int* in_sizes, int n_in,
                              void* d_out, int out_size, void* d_ws, size_t ws_size,
                              hipStream_t stream) {
    const float* img = (const float*)d_in[0];
    float* out = (float*)d_out;
    hipMemsetAsync(out, 0, sizeof(float), stream);  // d_out is poisoned 0xAA
    // 262144 work items: 256 planes x 8 row-segments x 128 column-groups
    scc_kernel<<<dim3(1024), dim3(256), 0, stream>>>(img, out);
}

// Round 2
// 468.375 us; speedup vs baseline: 1.1738x; 1.1738x over previous
//
#include <hip/hip_runtime.h>

// Problem constants (B,C,H,W) = (8,32,512,512), K=9
#define HH 512
#define WW 512
#define SEGS 8
#define SEGROWS 64   // HH / SEGS
#define CG 128       // float4 column-groups per row (WW/4)

__device__ __forceinline__ int imax(int a, int b) { return a > b ? a : b; }

// out = (1/8) * [ sum (81 + ch(h)*cw(w)) * x^2  -  2 * sum RowBox9(x) * ColBox9(x) ]
// Rings held in NAMED float4 registers (no arrays -> no scratch spill).
__global__ __launch_bounds__(256, 4) void scc_kernel(const float* __restrict__ img,
                                                     float* __restrict__ out) {
    const int tid   = blockIdx.x * 256 + threadIdx.x;
    const int g     = tid & (CG - 1);      // column group: cols [4g, 4g+3]
    const int rest  = tid >> 7;
    const int seg   = rest & (SEGS - 1);
    const int plane = rest >> 3;

    const float* base = img + (size_t)plane * (HH * WW);
    const int r0 = seg * SEGROWS;

    // per-column border weight cw(w) = #valid horizontal window positions
    float4 cw;
    {
        int w0 = 4 * g;
        cw.x = (float)(9 - imax(0, 4 - (w0 + 0)) - imax(0, (w0 + 0) - (WW - 5)));
        cw.y = (float)(9 - imax(0, 4 - (w0 + 1)) - imax(0, (w0 + 1) - (WW - 5)));
        cw.z = (float)(9 - imax(0, 4 - (w0 + 2)) - imax(0, (w0 + 2) - (WW - 5)));
        cw.w = (float)(9 - imax(0, 4 - (w0 + 3)) - imax(0, (w0 + 3) - (WW - 5)));
    }

    const float4 z4 = make_float4(0.f, 0.f, 0.f, 0.f);
    // x-ring: x0..x8 = x(r-9 .. r-1) before the shift of streamed row r
    float4 x0 = z4, x1 = z4, x2 = z4, x3 = z4, x4 = z4,
           x5 = z4, x6 = z4, x7 = z4, x8 = z4;
    // R-ring: q0..q4 = R(r-5 .. r-1) before shift
    float4 q0 = z4, q1 = z4, q2 = z4, q3 = z4, q4 = z4;
    float4 V = z4;             // after update: sum x(r-8 .. r)
    float accW = 0.f, accRV = 0.f;

#pragma unroll 8
    for (int i = 0; i < 72; ++i) {
        const int r = r0 - 4 + i;                 // streamed row
        const bool rowv = ((unsigned)r < (unsigned)HH);
        const float4* rowp = (const float4*)(base + (ptrdiff_t)r * WW);
        float4 lc = (rowv && g > 0)      ? rowp[g - 1] : z4;
        float4 cc = rowv                 ? rowp[g]     : z4;
        float4 rc = (rowv && g < CG - 1) ? rowp[g + 1] : z4;

        // sliding horizontal 9-sums for the 4 owned columns
        float R0 = ((lc.x + lc.y) + (lc.z + lc.w)) + ((cc.x + cc.y) + (cc.z + cc.w)) + rc.x;
        float R1 = R0 - lc.x + rc.y;
        float R2 = R1 - lc.y + rc.z;
        float R3 = R2 - lc.z + rc.w;
        float4 Rn = make_float4(R0, R1, R2, R3);

        // running vertical 9-sum: V = sum x(r-8..r)
        V.x += cc.x - x0.x;  V.y += cc.y - x0.y;
        V.z += cc.z - x0.z;  V.w += cc.w - x0.w;

        // shift rings (renamed away by unrolling)
        x0 = x1; x1 = x2; x2 = x3; x3 = x4; x4 = x5;
        x5 = x6; x6 = x7; x7 = x8; x8 = cc;
        q0 = q1; q1 = q2; q2 = q3; q3 = q4; q4 = Rn;
        // now x0..x8 = x(r-8..r) -> center x = x4 = x(r-4); q0 = R(r-4)

        if (i >= 8) {   // constant-folds per unrolled body
            const int h = r - 4;
            const float chf = (float)(9 - imax(0, 4 - h) - imax(0, h - (HH - 5)));
            float w0 = fmaf(chf, cw.x, 81.f);
            float w1 = fmaf(chf, cw.y, 81.f);
            float w2 = fmaf(chf, cw.z, 81.f);
            float w3 = fmaf(chf, cw.w, 81.f);
            accW = fmaf(w0 * x4.x, x4.x, accW);
            accW = fmaf(w1 * x4.y, x4.y, accW);
            accW = fmaf(w2 * x4.z, x4.z, accW);
            accW = fmaf(w3 * x4.w, x4.w, accW);
            accRV = fmaf(q0.x, V.x, accRV);
            accRV = fmaf(q0.y, V.y, accRV);
            accRV = fmaf(q0.z, V.z, accRV);
            accRV = fmaf(q0.w, V.w, accRV);
        }
    }

    float acc = accW - 2.f * accRV;

    // reduce: wave64 shuffle -> LDS -> one atomic per block
#pragma unroll
    for (int off = 32; off > 0; off >>= 1)
        acc += __shfl_xor(acc, off, 64);
    __shared__ float wsum[4];
    const int lane = threadIdx.x & 63;
    const int wv   = threadIdx.x >> 6;
    if (lane == 0) wsum[wv] = acc;
    __syncthreads();
    if (threadIdx.x == 0) {
        float s = (wsum[0] + wsum[1]) + (wsum[2] + wsum[3]);
        atomicAdd(out, 0.125f * s);  // mean over batch (B = 8)
    }
}

extern "C" void kernel_launch(void* const* d_in, const int* in_sizes, int n_in,
                              void* d_out, int out_size, void* d_ws, size_t ws_size,
                              hipStream_t stream) {
    const float* img = (const float*)d_in[0];
    float* out = (float*)d_out;
    hipMemsetAsync(out, 0, sizeof(float), stream);  // d_out is poisoned 0xAA
    // 262144 work items: 256 planes x 8 row-segments x 128 column-groups
    scc_kernel<<<dim3(1024), dim3(256), 0, stream>>>(img, out);
}

// Round 3
// 370.615 us; speedup vs baseline: 1.4835x; 1.2638x over previous
//
#include <hip/hip_runtime.h>

// Problem constants (B,C,H,W) = (8,32,512,512), K=9
#define HH 512
#define WW 512
#define SEGS 16
#define SEGROWS 32   // HH / SEGS
#define CG 128       // float4 column-groups per row (WW/4)

__device__ __forceinline__ int imax(int a, int b) { return a > b ? a : b; }
__device__ __forceinline__ int imin(int a, int b) { return a < b ? a : b; }

// out = (1/8) * [ sum (81 + ch(h)*cw(w)) * x^2  -  2 * sum RowBox9(x) * ColBox9(x) ]
// Branch-free: all loads unconditional (clamped addresses), zero-padding done
// with 0/1 float mask multiplies so loads pipeline across unrolled iterations.
__global__ __launch_bounds__(256, 4) void scc_kernel(const float* __restrict__ img,
                                                     float* __restrict__ out) {
    const int tid   = blockIdx.x * 256 + threadIdx.x;
    const int g     = tid & (CG - 1);      // column group: cols [4g, 4g+3]
    const int rest  = tid >> 7;
    const int seg   = rest & (SEGS - 1);
    const int plane = rest >> 4;

    const float* base = img + (size_t)plane * (HH * WW);
    const int r0 = seg * SEGROWS;

    // per-column border weight cw(w) = #valid horizontal window positions
    float4 cw;
    {
        int w0 = 4 * g;
        cw.x = (float)(9 - imax(0, 4 - (w0 + 0)) - imax(0, (w0 + 0) - (WW - 5)));
        cw.y = (float)(9 - imax(0, 4 - (w0 + 1)) - imax(0, (w0 + 1) - (WW - 5)));
        cw.z = (float)(9 - imax(0, 4 - (w0 + 2)) - imax(0, (w0 + 2) - (WW - 5)));
        cw.w = (float)(9 - imax(0, 4 - (w0 + 3)) - imax(0, (w0 + 3) - (WW - 5)));
    }

    // clamped neighbor offsets (bytes) + 0/1 edge masks, computed once
    const int offL = imax(g - 1, 0) * 16;
    const int offC = g * 16;
    const int offR = imin(g + 1, CG - 1) * 16;
    const float mL = (g > 0) ? 1.f : 0.f;
    const float mR = (g < CG - 1) ? 1.f : 0.f;

    const float4 z4 = make_float4(0.f, 0.f, 0.f, 0.f);
    // x-ring: x0..x8 = x(r-9 .. r-1) before the shift of streamed row r
    float4 x0 = z4, x1 = z4, x2 = z4, x3 = z4, x4 = z4,
           x5 = z4, x6 = z4, x7 = z4, x8 = z4;
    // R-ring: q0..q4 = R(r-5 .. r-1) before shift
    float4 q0 = z4, q1 = z4, q2 = z4, q3 = z4, q4 = z4;
    float4 V = z4;             // after update: sum x(r-8 .. r)
    float accW = 0.f, accRV = 0.f;

#pragma unroll 8
    for (int i = 0; i < SEGROWS + 8; ++i) {
        const int r  = r0 - 4 + i;                   // streamed row (may be OOB)
        const int rc_ = imin(imax(r, 0), HH - 1);    // clamped (uniform, scalar)
        const float m = ((unsigned)r < (unsigned)HH) ? 1.f : 0.f;  // uniform 0/1
        const char* rowb = (const char*)(base + (ptrdiff_t)rc_ * WW);

        float4 lcr = *(const float4*)(rowb + offL);  // unconditional loads
        float4 ccr = *(const float4*)(rowb + offC);
        float4 rcr = *(const float4*)(rowb + offR);

        const float a = mL * m, b = mR * m;
        float4 lc = make_float4(lcr.x * a, lcr.y * a, lcr.z * a, lcr.w * a);
        float4 cc = make_float4(ccr.x * m, ccr.y * m, ccr.z * m, ccr.w * m);
        float4 rc = make_float4(rcr.x * b, rcr.y * b, rcr.z * b, rcr.w * b);

        // sliding horizontal 9-sums for the 4 owned columns
        float R0 = ((lc.x + lc.y) + (lc.z + lc.w)) + ((cc.x + cc.y) + (cc.z + cc.w)) + rc.x;
        float R1 = R0 - lc.x + rc.y;
        float R2 = R1 - lc.y + rc.z;
        float R3 = R2 - lc.z + rc.w;
        float4 Rn = make_float4(R0, R1, R2, R3);

        // running vertical 9-sum: V = sum x(r-8..r)
        V.x += cc.x - x0.x;  V.y += cc.y - x0.y;
        V.z += cc.z - x0.z;  V.w += cc.w - x0.w;

        // shift rings (renamed away by unrolling)
        x0 = x1; x1 = x2; x2 = x3; x3 = x4; x4 = x5;
        x5 = x6; x6 = x7; x7 = x8; x8 = cc;
        q0 = q1; q1 = q2; q2 = q3; q3 = q4; q4 = Rn;
        // now x0..x8 = x(r-8..r) -> center x = x4 = x(r-4); q0 = R(r-4)

        if (i >= 8) {   // constant-folds per unrolled body
            const int h = r - 4;
            const float chf = (float)(9 - imax(0, 4 - h) - imax(0, h - (HH - 5)));
            float w0 = fmaf(chf, cw.x, 81.f);
            float w1 = fmaf(chf, cw.y, 81.f);
            float w2 = fmaf(chf, cw.z, 81.f);
            float w3 = fmaf(chf, cw.w, 81.f);
            accW = fmaf(w0 * x4.x, x4.x, accW);
            accW = fmaf(w1 * x4.y, x4.y, accW);
            accW = fmaf(w2 * x4.z, x4.z, accW);
            accW = fmaf(w3 * x4.w, x4.w, accW);
            accRV = fmaf(q0.x, V.x, accRV);
            accRV = fmaf(q0.y, V.y, accRV);
            accRV = fmaf(q0.z, V.z, accRV);
            accRV = fmaf(q0.w, V.w, accRV);
        }
    }

    float acc = accW - 2.f * accRV;

    // reduce: wave64 shuffle -> LDS -> one atomic per block
#pragma unroll
    for (int off = 32; off > 0; off >>= 1)
        acc += __shfl_xor(acc, off, 64);
    __shared__ float wsum[4];
    const int lane = threadIdx.x & 63;
    const int wv   = threadIdx.x >> 6;
    if (lane == 0) wsum[wv] = acc;
    __syncthreads();
    if (threadIdx.x == 0) {
        float s = (wsum[0] + wsum[1]) + (wsum[2] + wsum[3]);
        atomicAdd(out, 0.125f * s);  // mean over batch (B = 8)
    }
}

extern "C" void kernel_launch(void* const* d_in, const int* in_sizes, int n_in,
                              void* d_out, int out_size, void* d_ws, size_t ws_size,
                              hipStream_t stream) {
    const float* img = (const float*)d_in[0];
    float* out = (float*)d_out;
    hipMemsetAsync(out, 0, sizeof(float), stream);  // d_out is poisoned 0xAA
    // 524288 work items: 256 planes x 16 row-segments x 128 column-groups
    scc_kernel<<<dim3(2048), dim3(256), 0, stream>>>(img, out);
}